// Round 1
// baseline (204.239 us; speedup 1.0000x reference)
//
#include <hip/hip_runtime.h>

#define D 256
#define H 8
#define B 32
#define S 1024

// workspace layout (float offsets), all 16B-aligned
#define OFF_QK     0          // [H][D]            2048
#define OFF_SB     2048       // [H]               8 (+pad)
#define OFF_ATTN   2064       // [B][H][S]         262144
#define OFF_XWP    264208     // [B][8][H][D]      524288
#define OFF_XW     788496     // [B][H][D]         65536
#define OFF_POOLED 854032     // [B][H*D]          65536
// total 919568 floats = 3.68 MB

// qk[h][k] = sum_d Wk[k, h*D+d] * query[h][d];  sb[h] = sum_d bk[h*D+d]*query[h][d]
__global__ void k_prep(const float* __restrict__ Wk, const float* __restrict__ bk,
                       const float* __restrict__ query, float* __restrict__ qk,
                       float* __restrict__ sb) {
    const int h = blockIdx.x;
    const int t = threadIdx.x;   // t = k
    __shared__ float q[D];
    __shared__ float red[D];
    q[t] = query[h * D + t];
    __syncthreads();
    const float* wrow = Wk + (size_t)t * (D * H) + h * D;
    float acc = 0.f;
    for (int d = 0; d < D; d += 4) {
        float4 w  = *(const float4*)(wrow + d);
        float4 qq = *(const float4*)(&q[d]);   // broadcast
        acc += w.x * qq.x + w.y * qq.y + w.z * qq.z + w.w * qq.w;
    }
    qk[h * D + t] = acc;
    red[t] = bk[h * D + t] * q[t];
    __syncthreads();
    for (int st = 128; st > 0; st >>= 1) {
        if (t < st) red[t] += red[t + st];
        __syncthreads();
    }
    if (t == 0) sb[h] = red[0];
}

// scores[b,h,s] = x[b,s,:] . qk[h] + sb[h]; grid = B*32 blocks, 256 thr (4 waves x 8 rows)
__global__ void k_scores(const float* __restrict__ x, const float* __restrict__ qk,
                         const float* __restrict__ sb, float* __restrict__ attn) {
    const int blk   = blockIdx.x;
    const int b     = blk >> 5;
    const int stile = blk & 31;
    const int lane  = threadIdx.x & 63;
    const int wave  = threadIdx.x >> 6;
    float4 qk4[H];
    #pragma unroll
    for (int h = 0; h < H; h++) qk4[h] = *(const float4*)(qk + h * D + lane * 4);
    const float sbl = (lane < H) ? sb[lane] : 0.f;
    for (int r = 0; r < 8; r++) {
        const int s = stile * 32 + wave * 8 + r;
        const float4 xv = *(const float4*)(x + ((size_t)(b * S + s)) * D + lane * 4);
        float acc[H];
        #pragma unroll
        for (int h = 0; h < H; h++)
            acc[h] = xv.x * qk4[h].x + xv.y * qk4[h].y + xv.z * qk4[h].z + xv.w * qk4[h].w;
        #pragma unroll
        for (int m = 1; m < 64; m <<= 1) {
            #pragma unroll
            for (int h = 0; h < H; h++) acc[h] += __shfl_xor(acc[h], m);
        }
        // avoid dynamic reg indexing: cndmask chain
        float val = acc[0];
        #pragma unroll
        for (int h = 1; h < H; h++) if (lane == h) val = acc[h];
        if (lane < H)
            attn[((size_t)(b * H + lane)) * S + s] = val + sbl;
    }
}

// softmax over s for one (b,h) row; grid = B*H, 256 thr, 4 elems/thread
__global__ void k_softmax(float* __restrict__ attn) {
    float* row = attn + (size_t)blockIdx.x * S;
    const int t = threadIdx.x;
    const int wv = t >> 6, ln = t & 63;
    __shared__ float red[8];
    float4 v = *(float4*)(row + t * 4);
    float m = fmaxf(fmaxf(v.x, v.y), fmaxf(v.z, v.w));
    #pragma unroll
    for (int msk = 1; msk < 64; msk <<= 1) m = fmaxf(m, __shfl_xor(m, msk));
    if (ln == 0) red[wv] = m;
    __syncthreads();
    m = fmaxf(fmaxf(red[0], red[1]), fmaxf(red[2], red[3]));
    const float e0 = expf(v.x - m), e1 = expf(v.y - m), e2 = expf(v.z - m), e3 = expf(v.w - m);
    float sum = e0 + e1 + e2 + e3;
    #pragma unroll
    for (int msk = 1; msk < 64; msk <<= 1) sum += __shfl_xor(sum, msk);
    if (ln == 0) red[4 + wv] = sum;
    __syncthreads();
    const float inv = 1.f / (red[4] + red[5] + red[6] + red[7]);
    v.x = e0 * inv; v.y = e1 * inv; v.z = e2 * inv; v.w = e3 * inv;
    *(float4*)(row + t * 4) = v;
}

// partial weighted sums: xwp[b][c][h][d] = sum_{s in chunk c} attn[b,h,s]*x[b,s,d]
// grid = B*8 (8 chunks of 128 s), 256 thr (t = d)
__global__ void k_xwp(const float* __restrict__ x, const float* __restrict__ attn,
                      float* __restrict__ xwp) {
    const int b = blockIdx.x >> 3;
    const int c = blockIdx.x & 7;
    const int t = threadIdx.x;
    __shared__ float a[H][128];
    {
        const int h = t >> 5;
        const int i = (t & 31) * 4;
        *(float4*)(&a[h][i]) = *(const float4*)(attn + ((size_t)(b * H + h)) * S + c * 128 + i);
    }
    __syncthreads();
    float acc[H] = {};
    const float* xp = x + ((size_t)(b * S + c * 128)) * D + t;
    for (int s = 0; s < 128; s++) {
        const float xv = xp[(size_t)s * D];
        #pragma unroll
        for (int h = 0; h < H; h++) acc[h] += a[h][s] * xv;
    }
    #pragma unroll
    for (int h = 0; h < H; h++)
        xwp[((size_t)((b * 8 + c) * H + h)) * D + t] = acc[h];
}

// xw[b][h][d] = sum_c xwp[b][c][h][d]; grid = B*H, 256 thr
__global__ void k_xwc(const float* __restrict__ xwp, float* __restrict__ xw) {
    const int bh = blockIdx.x;
    const int b = bh >> 3, h = bh & 7;
    const int t = threadIdx.x;
    float acc = 0.f;
    #pragma unroll
    for (int c = 0; c < 8; c++)
        acc += xwp[((size_t)((b * 8 + c) * H + h)) * D + t];
    xw[(size_t)bh * D + t] = acc;
}

// pooled[b, h*D+j] = bv[h*D+j] + sum_d xw[b,h,d]*Wv[d, h*D+j]
// grid = 32 (h*4 + jtile), 256 thr: j = jt*64 + (t&63), bg = t>>6 handles 8 b's
__global__ void k_pooled(const float* __restrict__ xw, const float* __restrict__ Wv,
                         const float* __restrict__ bv, float* __restrict__ pooled) {
    const int h  = blockIdx.x >> 2;
    const int jt = blockIdx.x & 3;
    const int j  = jt * 64 + (threadIdx.x & 63);
    const int bg = threadIdx.x >> 6;
    float acc[8] = {};
    for (int d = 0; d < D; d += 4) {
        const float w0 = Wv[(size_t)(d + 0) * (D * H) + h * D + j];
        const float w1 = Wv[(size_t)(d + 1) * (D * H) + h * D + j];
        const float w2 = Wv[(size_t)(d + 2) * (D * H) + h * D + j];
        const float w3 = Wv[(size_t)(d + 3) * (D * H) + h * D + j];
        #pragma unroll
        for (int bi = 0; bi < 8; bi++) {
            const float4 xv = *(const float4*)(xw + ((size_t)((bg * 8 + bi) * H + h)) * D + d);
            acc[bi] += xv.x * w0 + xv.y * w1 + xv.z * w2 + xv.w * w3;
        }
    }
    const float bvj = bv[h * D + j];
    #pragma unroll
    for (int bi = 0; bi < 8; bi++)
        pooled[((size_t)(bg * 8 + bi)) * (D * H) + h * D + j] = acc[bi] + bvj;
}

// out init: out[b,j] = bo[j]
__global__ void k_outinit(const float* __restrict__ bo, float* __restrict__ out) {
    out[(size_t)blockIdx.x * D + threadIdx.x] = bo[threadIdx.x];
}

// out[b,j] += sum_{c in ctile} pooled[b,c]*Wo[c,j]; grid = 32 (ct*4 + jt), atomics over 8 ctiles
__global__ void k_out(const float* __restrict__ pooled, const float* __restrict__ Wo,
                      float* __restrict__ out) {
    const int jt = blockIdx.x & 3;
    const int ct = blockIdx.x >> 2;
    const int j  = jt * 64 + (threadIdx.x & 63);
    const int bg = threadIdx.x >> 6;
    const int c0 = ct * 256;
    float acc[8] = {};
    for (int cc = 0; cc < 256; cc += 4) {
        const float w0 = Wo[(size_t)(c0 + cc + 0) * D + j];
        const float w1 = Wo[(size_t)(c0 + cc + 1) * D + j];
        const float w2 = Wo[(size_t)(c0 + cc + 2) * D + j];
        const float w3 = Wo[(size_t)(c0 + cc + 3) * D + j];
        #pragma unroll
        for (int bi = 0; bi < 8; bi++) {
            const float4 pv = *(const float4*)(pooled + ((size_t)(bg * 8 + bi)) * (D * H) + c0 + cc);
            acc[bi] += pv.x * w0 + pv.y * w1 + pv.z * w2 + pv.w * w3;
        }
    }
    #pragma unroll
    for (int bi = 0; bi < 8; bi++)
        atomicAdd(out + ((size_t)(bg * 8 + bi)) * D + j, acc[bi]);
}

extern "C" void kernel_launch(void* const* d_in, const int* in_sizes, int n_in,
                              void* d_out, int out_size, void* d_ws, size_t ws_size,
                              hipStream_t stream) {
    const float* x     = (const float*)d_in[0];
    const float* Wk    = (const float*)d_in[1];
    const float* bk    = (const float*)d_in[2];
    const float* Wv    = (const float*)d_in[3];
    const float* bv    = (const float*)d_in[4];
    const float* query = (const float*)d_in[5];
    const float* Wo    = (const float*)d_in[6];
    const float* bo    = (const float*)d_in[7];
    float* out = (float*)d_out;
    float* ws  = (float*)d_ws;

    float* qk     = ws + OFF_QK;
    float* sb     = ws + OFF_SB;
    float* attn   = ws + OFF_ATTN;
    float* xwp    = ws + OFF_XWP;
    float* xw     = ws + OFF_XW;
    float* pooled = ws + OFF_POOLED;

    k_prep<<<dim3(H), dim3(D), 0, stream>>>(Wk, bk, query, qk, sb);
    k_scores<<<dim3(B * 32), dim3(256), 0, stream>>>(x, qk, sb, attn);
    k_softmax<<<dim3(B * H), dim3(256), 0, stream>>>(attn);
    k_xwp<<<dim3(B * 8), dim3(256), 0, stream>>>(x, attn, xwp);
    k_xwc<<<dim3(B * H), dim3(256), 0, stream>>>(xwp, xw);
    k_pooled<<<dim3(32), dim3(256), 0, stream>>>(xw, Wv, bv, pooled);
    k_outinit<<<dim3(B), dim3(D), 0, stream>>>(bo, out);
    k_out<<<dim3(32), dim3(256), 0, stream>>>(pooled, Wo, out);
}

// Round 2
// 155.375 us; speedup vs baseline: 1.3145x; 1.3145x over previous
//
#include <hip/hip_runtime.h>

#define D 256
#define H 8
#define B 32
#define S 1024

// workspace layout (float offsets), all 16B-aligned
#define OFF_QK     0          // [H][D]            2048
#define OFF_SB     2048       // [H]               8 (+pad)
#define OFF_ATTN   2064       // [B][H][S]         262144
#define OFF_XWP    264208     // [B][8][H][D]      524288
#define OFF_XW     788496     // [B][H][D]         65536
#define OFF_POOLED 854032     // [B][H*D]          65536
// total 919568 floats = 3.68 MB

// qk[h][k] = sum_d Wk[k, h*D+d] * query[h][d];  sb[h] = sum_d bk[h*D+d]*query[h][d]
__global__ void k_prep(const float* __restrict__ Wk, const float* __restrict__ bk,
                       const float* __restrict__ query, float* __restrict__ qk,
                       float* __restrict__ sb) {
    const int h = blockIdx.x;
    const int t = threadIdx.x;   // t = k
    __shared__ float q[D];
    __shared__ float red[D];
    q[t] = query[h * D + t];
    __syncthreads();
    const float* wrow = Wk + (size_t)t * (D * H) + h * D;
    float acc = 0.f;
    for (int d = 0; d < D; d += 4) {
        float4 w  = *(const float4*)(wrow + d);
        float4 qq = *(const float4*)(&q[d]);   // broadcast
        acc += w.x * qq.x + w.y * qq.y + w.z * qq.z + w.w * qq.w;
    }
    qk[h * D + t] = acc;
    red[t] = bk[h * D + t] * q[t];
    __syncthreads();
    for (int st = 128; st > 0; st >>= 1) {
        if (t < st) red[t] += red[t + st];
        __syncthreads();
    }
    if (t == 0) sb[h] = red[0];
}

// scores[b,h,s] = x[b,s,:] . qk[h] + sb[h]; grid = B*32 blocks, 256 thr (4 waves x 8 rows)
__global__ void k_scores(const float* __restrict__ x, const float* __restrict__ qk,
                         const float* __restrict__ sb, float* __restrict__ attn) {
    const int blk   = blockIdx.x;
    const int b     = blk >> 5;
    const int stile = blk & 31;
    const int lane  = threadIdx.x & 63;
    const int wave  = threadIdx.x >> 6;
    float4 qk4[H];
    #pragma unroll
    for (int h = 0; h < H; h++) qk4[h] = *(const float4*)(qk + h * D + lane * 4);
    const float sbl = (lane < H) ? sb[lane] : 0.f;
    for (int r = 0; r < 8; r++) {
        const int s = stile * 32 + wave * 8 + r;
        const float4 xv = *(const float4*)(x + ((size_t)(b * S + s)) * D + lane * 4);
        float acc[H];
        #pragma unroll
        for (int h = 0; h < H; h++)
            acc[h] = xv.x * qk4[h].x + xv.y * qk4[h].y + xv.z * qk4[h].z + xv.w * qk4[h].w;
        #pragma unroll
        for (int m = 1; m < 64; m <<= 1) {
            #pragma unroll
            for (int h = 0; h < H; h++) acc[h] += __shfl_xor(acc[h], m);
        }
        float val = acc[0];
        #pragma unroll
        for (int h = 1; h < H; h++) if (lane == h) val = acc[h];
        if (lane < H)
            attn[((size_t)(b * H + lane)) * S + s] = val + sbl;
    }
}

// softmax over s for one (b,h) row; grid = B*H, 256 thr, 4 elems/thread
__global__ void k_softmax(float* __restrict__ attn) {
    float* row = attn + (size_t)blockIdx.x * S;
    const int t = threadIdx.x;
    const int wv = t >> 6, ln = t & 63;
    __shared__ float red[8];
    float4 v = *(float4*)(row + t * 4);
    float m = fmaxf(fmaxf(v.x, v.y), fmaxf(v.z, v.w));
    #pragma unroll
    for (int msk = 1; msk < 64; msk <<= 1) m = fmaxf(m, __shfl_xor(m, msk));
    if (ln == 0) red[wv] = m;
    __syncthreads();
    m = fmaxf(fmaxf(red[0], red[1]), fmaxf(red[2], red[3]));
    const float e0 = expf(v.x - m), e1 = expf(v.y - m), e2 = expf(v.z - m), e3 = expf(v.w - m);
    float sum = e0 + e1 + e2 + e3;
    #pragma unroll
    for (int msk = 1; msk < 64; msk <<= 1) sum += __shfl_xor(sum, msk);
    if (ln == 0) red[4 + wv] = sum;
    __syncthreads();
    const float inv = 1.f / (red[4] + red[5] + red[6] + red[7]);
    v.x = e0 * inv; v.y = e1 * inv; v.z = e2 * inv; v.w = e3 * inv;
    *(float4*)(row + t * 4) = v;
}

// partial weighted sums: xwp[b][c][h][d] = sum_{s in chunk c} attn[b,h,s]*x[b,s,d]
// grid = B*8 (8 chunks of 128 s), 256 thr (t = d)
__global__ void k_xwp(const float* __restrict__ x, const float* __restrict__ attn,
                      float* __restrict__ xwp) {
    const int b = blockIdx.x >> 3;
    const int c = blockIdx.x & 7;
    const int t = threadIdx.x;
    __shared__ float a[H][128];
    {
        const int h = t >> 5;
        const int i = (t & 31) * 4;
        *(float4*)(&a[h][i]) = *(const float4*)(attn + ((size_t)(b * H + h)) * S + c * 128 + i);
    }
    __syncthreads();
    float acc[H] = {};
    const float* xp = x + ((size_t)(b * S + c * 128)) * D + t;
    for (int s = 0; s < 128; s++) {
        const float xv = xp[(size_t)s * D];
        #pragma unroll
        for (int h = 0; h < H; h++) acc[h] += a[h][s] * xv;
    }
    #pragma unroll
    for (int h = 0; h < H; h++)
        xwp[((size_t)((b * 8 + c) * H + h)) * D + t] = acc[h];
}

// xw[b][h][d] = sum_c xwp[b][c][h][d]; grid = B*H, 256 thr
__global__ void k_xwc(const float* __restrict__ xwp, float* __restrict__ xw) {
    const int bh = blockIdx.x;
    const int b = bh >> 3, h = bh & 7;
    const int t = threadIdx.x;
    float acc = 0.f;
    #pragma unroll
    for (int c = 0; c < 8; c++)
        acc += xwp[((size_t)((b * 8 + c) * H + h)) * D + t];
    xw[(size_t)bh * D + t] = acc;
}

// pooled[b, h*D+j] = bv[h*D+j] + sum_d xw[b,h,d]*Wv[d, h*D+j]
// grid = B*H = 256 blocks, 256 thr (t = j). xw row in LDS (broadcast reads),
// Wv streamed row-coalesced; 32x L2 reuse of Wv across b.
__global__ void k_pooled(const float* __restrict__ xw, const float* __restrict__ Wv,
                         const float* __restrict__ bv, float* __restrict__ pooled) {
    const int bh = blockIdx.x;            // b*H + h
    const int b = bh >> 3, h = bh & 7;
    const int j = threadIdx.x;
    __shared__ float xwL[D];
    xwL[j] = xw[(size_t)bh * D + j];
    __syncthreads();
    const float* wcol = Wv + h * D + j;   // row stride D*H
    float acc = 0.f;
    #pragma unroll 8
    for (int d = 0; d < D; d++)
        acc += xwL[d] * wcol[(size_t)d * (D * H)];
    pooled[(size_t)b * (D * H) + h * D + j] = acc + bv[h * D + j];
}

// out init: out[b,j] = bo[j]
__global__ void k_outinit(const float* __restrict__ bo, float* __restrict__ out) {
    out[(size_t)blockIdx.x * D + threadIdx.x] = bo[threadIdx.x];
}

// out[b,j] += sum_{c in kchunk} pooled[b,c]*Wo[c,j]
// grid = B*8 = 256 blocks (8 k-chunks of 256), 256 thr (t = j), atomicAdd combine.
__global__ void k_out(const float* __restrict__ pooled, const float* __restrict__ Wo,
                      float* __restrict__ out) {
    const int b  = blockIdx.x >> 3;
    const int kc = blockIdx.x & 7;
    const int j  = threadIdx.x;
    __shared__ float pL[256];
    pL[j] = pooled[(size_t)b * (D * H) + kc * 256 + j];
    __syncthreads();
    const float* wp = Wo + (size_t)(kc * 256) * D + j;   // row stride D
    float acc = 0.f;
    #pragma unroll 8
    for (int c = 0; c < 256; c++)
        acc += pL[c] * wp[(size_t)c * D];
    atomicAdd(out + (size_t)b * D + j, acc);
}

extern "C" void kernel_launch(void* const* d_in, const int* in_sizes, int n_in,
                              void* d_out, int out_size, void* d_ws, size_t ws_size,
                              hipStream_t stream) {
    const float* x     = (const float*)d_in[0];
    const float* Wk    = (const float*)d_in[1];
    const float* bk    = (const float*)d_in[2];
    const float* Wv    = (const float*)d_in[3];
    const float* bv    = (const float*)d_in[4];
    const float* query = (const float*)d_in[5];
    const float* Wo    = (const float*)d_in[6];
    const float* bo    = (const float*)d_in[7];
    float* out = (float*)d_out;
    float* ws  = (float*)d_ws;

    float* qk     = ws + OFF_QK;
    float* sb     = ws + OFF_SB;
    float* attn   = ws + OFF_ATTN;
    float* xwp    = ws + OFF_XWP;
    float* xw     = ws + OFF_XW;
    float* pooled = ws + OFF_POOLED;

    k_prep<<<dim3(H), dim3(D), 0, stream>>>(Wk, bk, query, qk, sb);
    k_scores<<<dim3(B * 32), dim3(256), 0, stream>>>(x, qk, sb, attn);
    k_softmax<<<dim3(B * H), dim3(256), 0, stream>>>(attn);
    k_xwp<<<dim3(B * 8), dim3(256), 0, stream>>>(x, attn, xwp);
    k_xwc<<<dim3(B * H), dim3(256), 0, stream>>>(xwp, xw);
    k_pooled<<<dim3(B * H), dim3(256), 0, stream>>>(xw, Wv, bv, pooled);
    k_outinit<<<dim3(B), dim3(D), 0, stream>>>(bo, out);
    k_out<<<dim3(B * 8), dim3(256), 0, stream>>>(pooled, Wo, out);
}

// Round 3
// 127.703 us; speedup vs baseline: 1.5993x; 1.2167x over previous
//
#include <hip/hip_runtime.h>

#define D 256
#define H 8
#define B 32
#define S 1024
#define SCH 16      // s-chunks per batch
#define SCS 64      // s per chunk

// workspace layout (float offsets)
#define OFF_QK     0                       // [H][D]              2048
#define OFF_SB     2048                    // [H]                 8
#define OFF_ML     2056                    // [B][SCH][H] float2  8192 floats
#define OFF_XWP    10248                   // [B][SCH][H][D]      1048576
#define OFF_POOLED 1058824                 // [B][H*D]            65536
// total ~4.5 MB

// qk[h][k] = sum_d Wk[k, h*D+d]*q[h][d]; sb[h] = bk_h . q[h]; also out[b]=bo.
// grid = H*8 = 64 blocks, 256 thr: thread = (k_local = t>>3) x (dq = t&7, 32 d's each)
__global__ void k_prep(const float* __restrict__ Wk, const float* __restrict__ bk,
                       const float* __restrict__ query, const float* __restrict__ bo,
                       float* __restrict__ qk, float* __restrict__ sb,
                       float* __restrict__ out) {
    const int h  = blockIdx.x >> 3;
    const int kc = blockIdx.x & 7;
    const int t  = threadIdx.x;
    __shared__ float qsh[D];
    __shared__ float red[D];
    qsh[t] = query[h * D + t];
    __syncthreads();
    const int kl = t >> 3;
    const int dq = t & 7;
    const int k  = kc * 32 + kl;
    const float* wrow = Wk + (size_t)k * (D * H) + h * D;
    float acc = 0.f;
    #pragma unroll
    for (int i = 0; i < 8; i++) {
        const int d = i * 32 + dq * 4;     // 8 lanes cover 128B contiguous per i
        const float4 w = *(const float4*)(wrow + d);
        acc += w.x * qsh[d] + w.y * qsh[d + 1] + w.z * qsh[d + 2] + w.w * qsh[d + 3];
    }
    acc += __shfl_xor(acc, 1);
    acc += __shfl_xor(acc, 2);
    acc += __shfl_xor(acc, 4);
    if (dq == 0) qk[h * D + k] = acc;
    if (kc == 0) {                          // block-uniform branch
        red[t] = bk[h * D + t] * qsh[t];
        __syncthreads();
        for (int st = 128; st > 0; st >>= 1) {
            if (t < st) red[t] += red[t + st];
            __syncthreads();
        }
        if (t == 0) sb[h] = red[0];
    }
    if (h == 0) {                           // out init: 8 blocks x 4 b each
        const float bov = bo[t];
        #pragma unroll
        for (int bb = 0; bb < 4; bb++)
            out[(size_t)(kc * 4 + bb) * D + t] = bov;
    }
}

// One (b, chunk): scores -> chunk softmax (m,l saved) -> unnormalized weighted sum.
// grid = B*SCH = 512 blocks, 256 thr.
__global__ void k_fused(const float* __restrict__ x, const float* __restrict__ qk,
                        const float* __restrict__ sb, float* __restrict__ xwp,
                        float2* __restrict__ mlbuf) {
    const int b  = blockIdx.x >> 4;
    const int c  = blockIdx.x & 15;
    const int s0 = c * SCS;
    const int t  = threadIdx.x;
    __shared__ float qkL[H * D];            // 8 KB
    __shared__ float sc[SCS][H];            // 2 KB, scores then p
    #pragma unroll
    for (int i = 0; i < 8; i++) qkL[i * 256 + t] = qk[i * 256 + t];
    __syncthreads();

    // pass A: thread = (s_local = t>>2) x (dq = t&3, 64 d's each), 2-step shuffle reduce
    {
        const int sl = t >> 2;
        const int dq = t & 3;
        const int d0 = dq * 64;
        float accA[H] = {};
        const float* xrow = x + ((size_t)(b * S + s0 + sl)) * D + d0;
        #pragma unroll 4
        for (int i = 0; i < 16; i++) {
            const float4 xv = *(const float4*)(xrow + i * 4);
            #pragma unroll
            for (int hh = 0; hh < H; hh++) {
                const float4 qv = *(const float4*)(&qkL[hh * D + d0 + i * 4]);
                accA[hh] += xv.x * qv.x + xv.y * qv.y + xv.z * qv.z + xv.w * qv.w;
            }
        }
        #pragma unroll
        for (int hh = 0; hh < H; hh++) {
            accA[hh] += __shfl_xor(accA[hh], 1);
            accA[hh] += __shfl_xor(accA[hh], 2);
        }
        if (dq == 0) {
            #pragma unroll
            for (int hh = 0; hh < H; hh++)
                sc[sl][hh] = accA[hh] + sb[hh];
        }
    }
    __syncthreads();

    // chunk softmax over 64 s, per h: threads t = h*32 + u
    {
        const int hh = t >> 5;
        const int u  = t & 31;
        const float v0 = sc[u][hh], v1 = sc[u + 32][hh];
        float m = fmaxf(v0, v1);
        #pragma unroll
        for (int msk = 1; msk < 32; msk <<= 1) m = fmaxf(m, __shfl_xor(m, msk));
        const float e0 = __expf(v0 - m), e1 = __expf(v1 - m);
        float sum = e0 + e1;
        #pragma unroll
        for (int msk = 1; msk < 32; msk <<= 1) sum += __shfl_xor(sum, msk);
        sc[u][hh] = e0;
        sc[u + 32][hh] = e1;
        if (u == 0) mlbuf[((size_t)(b * SCH + c)) * H + hh] = make_float2(m, sum);
    }
    __syncthreads();

    // pass B: thread = d; x re-read from L2; p broadcast from LDS
    {
        float acc2[H] = {};
        const float* xp = x + ((size_t)(b * S + s0)) * D + t;
        for (int s = 0; s < SCS; s++) {
            const float xv = xp[(size_t)s * D];
            const float4 pa = *(const float4*)(&sc[s][0]);
            const float4 pb = *(const float4*)(&sc[s][4]);
            acc2[0] += pa.x * xv; acc2[1] += pa.y * xv;
            acc2[2] += pa.z * xv; acc2[3] += pa.w * xv;
            acc2[4] += pb.x * xv; acc2[5] += pb.y * xv;
            acc2[6] += pb.z * xv; acc2[7] += pb.w * xv;
        }
        #pragma unroll
        for (int hh = 0; hh < H; hh++)
            xwp[(((size_t)(b * SCH + c)) * H + hh) * D + t] = acc2[hh];
    }
}

// combine chunks (rescale by exp(m_c-M)/L) + pooled GEMV vs Wv.
// grid = B*H = 256 blocks, 256 thr (t = j)
__global__ void k_pooled(const float* __restrict__ xwp, const float2* __restrict__ mlbuf,
                         const float* __restrict__ Wv, const float* __restrict__ bv,
                         float* __restrict__ pooled) {
    const int bh = blockIdx.x;
    const int b = bh >> 3, h = bh & 7;
    const int j = threadIdx.x;
    __shared__ float xwL[D];
    __shared__ float scaleL[SCH];
    __shared__ float2 mlL[SCH];
    if (j < SCH) mlL[j] = mlbuf[((size_t)(b * SCH + j)) * H + h];
    __syncthreads();
    if (j == 0) {
        float M = -1e30f;
        for (int cc = 0; cc < SCH; cc++) M = fmaxf(M, mlL[cc].x);
        float L = 0.f;
        for (int cc = 0; cc < SCH; cc++) L += mlL[cc].y * __expf(mlL[cc].x - M);
        const float invL = 1.f / L;
        for (int cc = 0; cc < SCH; cc++) scaleL[cc] = __expf(mlL[cc].x - M) * invL;
    }
    __syncthreads();
    float acc = 0.f;
    #pragma unroll
    for (int cc = 0; cc < SCH; cc++)
        acc += xwp[(((size_t)(b * SCH + cc)) * H + h) * D + j] * scaleL[cc];
    xwL[j] = acc;
    __syncthreads();
    const float* wcol = Wv + h * D + j;     // row stride D*H
    float a2 = 0.f;
    #pragma unroll 8
    for (int d = 0; d < D; d++)
        a2 += xwL[d] * wcol[(size_t)d * (D * H)];
    pooled[(size_t)b * (D * H) + h * D + j] = a2 + bv[h * D + j];
}

// out[b,j] += sum_{k in chunk} pooled[b,k]*Wo[k,j]; out pre-initialized to bo in k_prep.
// grid = B*8 = 256 blocks, 256 thr (t = j)
__global__ void k_out(const float* __restrict__ pooled, const float* __restrict__ Wo,
                      float* __restrict__ out) {
    const int b  = blockIdx.x >> 3;
    const int kc = blockIdx.x & 7;
    const int j  = threadIdx.x;
    __shared__ float pL[256];
    pL[j] = pooled[(size_t)b * (D * H) + kc * 256 + j];
    __syncthreads();
    const float* wp = Wo + (size_t)(kc * 256) * D + j;
    float acc = 0.f;
    #pragma unroll 8
    for (int cc = 0; cc < 256; cc++)
        acc += pL[cc] * wp[(size_t)cc * D];
    atomicAdd(out + (size_t)b * D + j, acc);
}

extern "C" void kernel_launch(void* const* d_in, const int* in_sizes, int n_in,
                              void* d_out, int out_size, void* d_ws, size_t ws_size,
                              hipStream_t stream) {
    const float* x     = (const float*)d_in[0];
    const float* Wk    = (const float*)d_in[1];
    const float* bk    = (const float*)d_in[2];
    const float* Wv    = (const float*)d_in[3];
    const float* bv    = (const float*)d_in[4];
    const float* query = (const float*)d_in[5];
    const float* Wo    = (const float*)d_in[6];
    const float* bo    = (const float*)d_in[7];
    float* out = (float*)d_out;
    float* ws  = (float*)d_ws;

    float*  qk     = ws + OFF_QK;
    float*  sb     = ws + OFF_SB;
    float2* mlbuf  = (float2*)(ws + OFF_ML);
    float*  xwp    = ws + OFF_XWP;
    float*  pooled = ws + OFF_POOLED;

    k_prep<<<dim3(H * 8), dim3(256), 0, stream>>>(Wk, bk, query, bo, qk, sb, out);
    k_fused<<<dim3(B * SCH), dim3(256), 0, stream>>>(x, qk, sb, xwp, mlbuf);
    k_pooled<<<dim3(B * H), dim3(256), 0, stream>>>(xwp, mlbuf, Wv, bv, pooled);
    k_out<<<dim3(B * 8), dim3(256), 0, stream>>>(pooled, Wo, out);
}